// Round 4
// baseline (103.838 us; speedup 1.0000x reference)
//
#include <hip/hip_runtime.h>
#include <hip/hip_bf16.h>

// Problem constants
#define B_   256
#define N_   64
#define D_   128
#define E_   8
#define T_   80
#define H_   256   // 2*D
#define O_   160   // T*2
#define NTOK 63    // tokens 1..63 used

typedef __bf16 bf16x8 __attribute__((ext_vector_type(8)));
typedef float  f32x4  __attribute__((ext_vector_type(4)));
typedef unsigned short u16x8 __attribute__((ext_vector_type(8)));
typedef unsigned short u16x4 __attribute__((ext_vector_type(4)));

struct Route { int e0, e1; float g0, g1; };   // 16 B

__device__ __forceinline__ unsigned short f2bf(float f) {
    unsigned int u = __builtin_bit_cast(unsigned int, f);
    u += 0x7FFFu + ((u >> 16) & 1u);   // round-to-nearest-even
    return (unsigned short)(u >> 16);
}

// ---------------- Kernel 1: weight transpose + router, one grid ----------
// blocks 0..255   : w1 (E,D,H) f32 -> w1t (E,H,D) bf16   (32x32 tiles)
// blocks 256..575 : w2 (E,H,O) f32 -> w2t (E,O,H) bf16   (32x32 tiles)
// blocks 576..831 : routing for batch b = bid-576 -> rt[b]
__global__ __launch_bounds__(256)
void prep_route(const float* __restrict__ x,
                const float* __restrict__ rw,
                const float* __restrict__ rb,
                const float* __restrict__ w1,
                const float* __restrict__ w2,
                unsigned short* __restrict__ w1t,
                unsigned short* __restrict__ w2t,
                Route* __restrict__ rt) {
    __shared__ float smem[1184];   // tile[32][33] (1056) | part[8][128]+pooled[128]
    const int bid = blockIdx.x;
    const int t = threadIdx.x;

    if (bid < 576) {
        // ------- transpose branch -------
        const int r  = t >> 3;          // 0..31
        const int c4 = (t & 7) * 4;     // 0..28
        const float* src; unsigned short* dst;
        int src_ld, dst_ld;
        size_t soff, doff;
        if (bid < 256) {                 // w1: per-e (128 x 256) -> (256 x 128)
            int e = bid >> 5, rest = bid & 31;
            int dt = rest >> 3, ht = rest & 7;
            soff = ((size_t)e * 128 + dt * 32) * 256 + ht * 32; src_ld = 256;
            doff = ((size_t)e * 256 + ht * 32) * 128 + dt * 32; dst_ld = 128;
            src = w1; dst = w1t;
        } else {                         // w2: per-e (256 x 160) -> (160 x 256)
            int id = bid - 256;
            int e = id / 40, rest = id % 40;
            int ht = rest / 5, ot = rest % 5;
            soff = ((size_t)e * 256 + ht * 32) * 160 + ot * 32; src_ld = 160;
            doff = ((size_t)e * 160 + ot * 32) * 256 + ht * 32; dst_ld = 256;
            src = w2; dst = w2t;
        }
        float4 v = *(const float4*)(src + soff + (size_t)r * src_ld + c4);
        smem[r * 33 + c4 + 0] = v.x; smem[r * 33 + c4 + 1] = v.y;
        smem[r * 33 + c4 + 2] = v.z; smem[r * 33 + c4 + 3] = v.w;
        __syncthreads();
        const int c  = t >> 3;
        const int r4 = (t & 7) * 4;
        u16x4 h4;
        h4[0] = f2bf(smem[(r4 + 0) * 33 + c]); h4[1] = f2bf(smem[(r4 + 1) * 33 + c]);
        h4[2] = f2bf(smem[(r4 + 2) * 33 + c]); h4[3] = f2bf(smem[(r4 + 3) * 33 + c]);
        *(u16x4*)(dst + doff + (size_t)c * dst_ld + r4) = h4;
    } else {
        // ------- routing branch: pooled mean -> logits -> softmax -> top2 ---
        const int b = bid - 576;
        float* part = smem;              // [8][128]
        float* pooled = smem + 1024;     // [128]
        const int c4 = (t & 31) * 4;     // float4 col 0..124
        const int rr = t >> 5;           // 0..7
        const float* xb = x + ((size_t)b * N_ + 1) * D_;
        float4 ps = make_float4(0.f, 0.f, 0.f, 0.f);
        for (int row = rr; row < NTOK; row += 8) {
            float4 v = *(const float4*)(xb + (size_t)row * D_ + c4);
            ps.x += v.x; ps.y += v.y; ps.z += v.z; ps.w += v.w;
        }
        *(float4*)&part[rr * 128 + c4] = ps;
        __syncthreads();
        if (t < 128) {
            float s = 0.f;
            #pragma unroll
            for (int i = 0; i < 8; ++i) s += part[i * 128 + t];
            pooled[t] = s * (1.f / 63.f);
        }
        __syncthreads();
        if (t < 64) {
            int e  = t >> 3;        // 0..7
            int dg = t & 7;         // dim group of 16
            float p = 0.f;
            #pragma unroll
            for (int i = 0; i < 16; ++i)
                p += pooled[dg * 16 + i] * rw[(dg * 16 + i) * E_ + e];
            p += __shfl_xor(p, 1); p += __shfl_xor(p, 2); p += __shfl_xor(p, 4);
            // lg gather must run with ALL 64 lanes active: ds_bpermute reads
            // from inactive source lanes return 0 (the R3 bug).
            float lg[E_];
            #pragma unroll
            for (int e2 = 0; e2 < E_; ++e2) lg[e2] = __shfl(p, e2 * 8) + rb[e2];
            if (t == 0) {
                float mx = lg[0];
                for (int i = 1; i < E_; ++i) mx = fmaxf(mx, lg[i]);
                float pr[E_]; float den = 0.f;
                for (int i = 0; i < E_; ++i) { pr[i] = expf(lg[i] - mx); den += pr[i]; }
                int i0 = 0;
                for (int i = 1; i < E_; ++i) if (pr[i] > pr[i0]) i0 = i;  // first on tie
                int i1 = (i0 == 0) ? 1 : 0;
                for (int i = 0; i < E_; ++i) if (i != i0 && pr[i] > pr[i1]) i1 = i;
                float inv = 1.f / den;
                Route r; r.e0 = i0; r.e1 = i1;
                r.g0 = pr[i0] * inv; r.g1 = pr[i1] * inv;
                rt[b] = r;
            }
        }
    }
}

// ---------------- Kernel 2: main MoE (top-2 experts, bf16 MFMA) ----------------
// grid = (2 token-halves, B), block = 256 threads (4 waves) -> 2 blocks/CU.
// rt[b] loaded first => weight addresses known immediately; weight loads
// overlap xa staging. Per expert: h=relu(xa@w1+b1)*g -> swizzled LDS;
// acc2 += h@w2 over both experts; single fp32 store.
__global__ __launch_bounds__(256)
void moe_main(const float* __restrict__ x,
              const float* __restrict__ b1,
              const float* __restrict__ b2,
              const unsigned short* __restrict__ w1t,
              const unsigned short* __restrict__ w2t,
              const Route* __restrict__ rt,
              float* __restrict__ out) {
    const int half = blockIdx.x;      // 0,1
    const int b    = blockIdx.y;      // 0..255
    const int m0   = half * 32;
    const int t    = threadIdx.x;
    const int wv   = t >> 6;          // wave 0..3
    const int lane = t & 63;
    const int q    = lane >> 4;       // quad 0..3
    const int r16  = lane & 15;

    __shared__ unsigned short xa_lds[32 * 128];  // 8 KiB, XOR-swizzled rows
    __shared__ unsigned short h_lds[32 * 256];   // 16 KiB, XOR-swizzled rows

    // routing first: resolves weight base addresses before staging
    const Route rr = rt[b];

    // ---- stage xa (f32 -> bf16, swizzled) ----
    {
        int row  = t >> 3;            // 0..31
        int col0 = (t & 7) * 16;      // 0..112
        int n = m0 + row;
        bool valid = (n < NTOK);
        const float* src = x + ((size_t)b * N_ + (1 + n)) * D_ + col0;
        #pragma unroll
        for (int c = 0; c < 4; ++c) {
            float4 v;
            if (valid) v = *(const float4*)(src + c * 4);
            else       v = make_float4(0.f, 0.f, 0.f, 0.f);
            u16x4 h4;
            h4[0] = f2bf(v.x); h4[1] = f2bf(v.y); h4[2] = f2bf(v.z); h4[3] = f2bf(v.w);
            int col = col0 + c * 4;
            *(u16x4*)&xa_lds[row * 128 + (col ^ ((row & 7) << 3))] = h4;
        }
    }

    const f32x4 z4 = {0.f, 0.f, 0.f, 0.f};
    f32x4 acc2[2][3];
    #pragma unroll
    for (int mt = 0; mt < 2; ++mt)
        #pragma unroll
        for (int j = 0; j < 3; ++j) acc2[mt][j] = z4;

    __syncthreads();

    #pragma unroll
    for (int s = 0; s < 2; ++s) {
        const int   e = s ? rr.e1 : rr.e0;
        const float g = s ? rr.g1 : rr.g0;
        const unsigned short* w1e = w1t + (size_t)e * H_ * D_;

        // ---- layer 1: acc1 = xa(32x128) @ w1e(cols wv*64..) ----
        f32x4 acc1[2][4];
        #pragma unroll
        for (int mt = 0; mt < 2; ++mt)
            #pragma unroll
            for (int nt = 0; nt < 4; ++nt) acc1[mt][nt] = z4;

        #pragma unroll
        for (int ks = 0; ks < 4; ++ks) {
            int col0k = ks * 32 + q * 8;
            int row0 = r16, row1 = 16 + r16;
            bf16x8 a0 = __builtin_bit_cast(bf16x8,
                *(const u16x8*)&xa_lds[row0 * 128 + (col0k ^ ((row0 & 7) << 3))]);
            bf16x8 a1 = __builtin_bit_cast(bf16x8,
                *(const u16x8*)&xa_lds[row1 * 128 + (col0k ^ ((row1 & 7) << 3))]);
            #pragma unroll
            for (int nt = 0; nt < 4; ++nt) {
                int col = wv * 64 + nt * 16 + r16;
                bf16x8 bb = __builtin_bit_cast(bf16x8,
                    *(const u16x8*)(w1e + (size_t)col * D_ + col0k));
                acc1[0][nt] = __builtin_amdgcn_mfma_f32_16x16x32_bf16(a0, bb, acc1[0][nt], 0, 0, 0);
                acc1[1][nt] = __builtin_amdgcn_mfma_f32_16x16x32_bf16(a1, bb, acc1[1][nt], 0, 0, 0);
            }
        }

        // slot 1 must wait until all waves finished reading h_lds of slot 0
        if (s == 1) __syncthreads();

        // ---- relu + bias + gate -> swizzled LDS bf16 ----
        float b1v[4];
        #pragma unroll
        for (int nt = 0; nt < 4; ++nt) b1v[nt] = b1[e * H_ + wv * 64 + nt * 16 + r16];
        #pragma unroll
        for (int mt = 0; mt < 2; ++mt)
            #pragma unroll
            for (int nt = 0; nt < 4; ++nt) {
                int col = wv * 64 + nt * 16 + r16;
                #pragma unroll
                for (int rg = 0; rg < 4; ++rg) {
                    int row = mt * 16 + q * 4 + rg;
                    float v = acc1[mt][nt][rg] + b1v[nt];
                    v = fmaxf(v, 0.f) * g;
                    h_lds[row * 256 + (col ^ ((row & 7) << 3))] = f2bf(v);
                }
            }
        __syncthreads();

        // ---- layer 2: acc2 += h(32x256) @ w2e(10 col-tiles over 4 waves) ----
        const unsigned short* w2e = w2t + (size_t)e * O_ * H_;
        #pragma unroll
        for (int ks = 0; ks < 8; ++ks) {
            int col0k = ks * 32 + q * 8;
            int row0 = r16, row1 = 16 + r16;
            bf16x8 a0 = __builtin_bit_cast(bf16x8,
                *(const u16x8*)&h_lds[row0 * 256 + (col0k ^ ((row0 & 7) << 3))]);
            bf16x8 a1 = __builtin_bit_cast(bf16x8,
                *(const u16x8*)&h_lds[row1 * 256 + (col0k ^ ((row1 & 7) << 3))]);
            #pragma unroll
            for (int j = 0; j < 3; ++j) {
                int nt2 = wv + j * 4;
                if (nt2 < 10) {
                    int col = nt2 * 16 + r16;
                    bf16x8 bb = __builtin_bit_cast(bf16x8,
                        *(const u16x8*)(w2e + (size_t)col * H_ + col0k));
                    acc2[0][j] = __builtin_amdgcn_mfma_f32_16x16x32_bf16(a0, bb, acc2[0][j], 0, 0, 0);
                    acc2[1][j] = __builtin_amdgcn_mfma_f32_16x16x32_bf16(a1, bb, acc2[1][j], 0, 0, 0);
                }
            }
        }
    }

    // ---- epilogue: add gated b2, store fp32 ----
    #pragma unroll
    for (int j = 0; j < 3; ++j) {
        int nt2 = wv + j * 4;
        if (nt2 < 10) {
            int col = nt2 * 16 + r16;
            float bias = rr.g0 * b2[rr.e0 * O_ + col] + rr.g1 * b2[rr.e1 * O_ + col];
            #pragma unroll
            for (int mt = 0; mt < 2; ++mt)
                #pragma unroll
                for (int rg = 0; rg < 4; ++rg) {
                    int row = mt * 16 + q * 4 + rg;
                    int n = m0 + row;
                    if (n < NTOK)
                        out[((size_t)b * NTOK + n) * O_ + col] = acc2[mt][j][rg] + bias;
                }
        }
    }
}

// ---------------- launch ----------------
extern "C" void kernel_launch(void* const* d_in, const int* in_sizes, int n_in,
                              void* d_out, int out_size, void* d_ws, size_t ws_size,
                              hipStream_t stream) {
    const float* x  = (const float*)d_in[0];
    const float* rw = (const float*)d_in[1];
    const float* rb = (const float*)d_in[2];
    const float* w1 = (const float*)d_in[3];
    const float* b1 = (const float*)d_in[4];
    const float* w2 = (const float*)d_in[5];
    const float* b2 = (const float*)d_in[6];
    float* out = (float*)d_out;

    unsigned short* w1t = (unsigned short*)d_ws;            // E*H*D bf16 = 512 KiB
    unsigned short* w2t = w1t + (size_t)E_ * H_ * D_;       // E*O*H bf16 = 640 KiB
    Route* rt = (Route*)(w2t + (size_t)E_ * O_ * H_);       // 4 KiB, 16B-aligned

    prep_route<<<832, 256, 0, stream>>>(x, rw, rb, w1, w2, w1t, w2t, rt);
    moe_main<<<dim3(2, B_), 256, 0, stream>>>(x, b1, b2, w1t, w2t, rt, out);
}